// Round 11
// baseline (253.363 us; speedup 1.0000x reference)
//
#include <hip/hip_runtime.h>
#include <hip/hip_bf16.h>

// B=2, N=2048, E=1024, H=16, D=64 (MQA). out = softmax(causal(QK^T/8)) V @ Wo + bo
//
// Round 11:
//   - attn: 128-row q-tiles, 8 waves/block (512 thr). Same r9 math/staging/swizzle;
//     barriers amortized 2x, LDS = QP(16K) + K/V dbuf(32K) = 48KB -> up to 3 blk/CU.
//     Grid 512, heavy-first (LPT). (r10 lesson: keep LDS staging for K/V —
//     direct-global frags exposed ~200cy VMEM latency per iter and regressed.)
//   - GEMMs: back to r3-proven 128x128 tile (out-proj = exactly 256 blocks),
//     with r9's fused Vt-write epilogue on the QKV GEMM.
//   - prep: r9 verbatim.

#define NQ 2048
#define BATCH 2
#define HEADS 16
#define HD 64
#define EMB 1024
#define NKV 1152   // 1024 Q cols + 64 K + 64 V

typedef short s16x8 __attribute__((ext_vector_type(8)));
typedef float f32x4 __attribute__((ext_vector_type(4)));
typedef unsigned short ushort_t;

__device__ __forceinline__ ushort_t f2bf(float f) {
    unsigned u = __builtin_bit_cast(unsigned, f);
    u += 0x7fff + ((u >> 16) & 1);          // RNE
    return (ushort_t)(u >> 16);
}

__device__ __forceinline__ void store_out(float* p, float v) { *p = v; }
__device__ __forceinline__ void store_out(ushort_t* p, float v) { *p = f2bf(v); }

// async global->LDS, 16B per lane. LDS dest = wave-uniform base + lane*16.
#define GL16(g, l)                                                                  \
    __builtin_amdgcn_global_load_lds(                                               \
        (const __attribute__((address_space(1))) unsigned int*)(g),                 \
        (__attribute__((address_space(3))) unsigned int*)(l), 16, 0, 0)

// Fused prep: blocks [0,4096): x fp32->bf16. Blocks [4096,6272): 32x32 transpose
// tiles of Wq/Wk/Wv (packed into Wqkv_t, N-major) and Wo -> Wo_t.
__global__ __launch_bounds__(256) void prep(const float* __restrict__ x,
                                            const float* __restrict__ Wq,
                                            const float* __restrict__ Wk,
                                            const float* __restrict__ Wv,
                                            const float* __restrict__ Wo,
                                            ushort_t* __restrict__ xb,
                                            ushort_t* __restrict__ Wqkv_t,
                                            ushort_t* __restrict__ Wo_t) {
    const int bid = blockIdx.x, t = threadIdx.x;
    if (bid < 4096) {
        const int i = bid * 1024 + t * 4;
        const float4 v = *(const float4*)&x[i];
        ushort_t o[4] = {f2bf(v.x), f2bf(v.y), f2bf(v.z), f2bf(v.w)};
        *(uint2*)&xb[i] = *(uint2*)o;
        return;
    }
    int tb = bid - 4096;
    const float* src; ushort_t* dst; int N, n0, k0;
    if (tb < 1024)      { src = Wq; N = 1024; dst = Wqkv_t;
                          n0 = (tb & 31) * 32; k0 = (tb >> 5) * 32; }
    else if (tb < 1088) { tb -= 1024; src = Wk; N = 64; dst = Wqkv_t + (size_t)1024 * EMB;
                          n0 = (tb & 1) * 32; k0 = (tb >> 1) * 32; }
    else if (tb < 1152) { tb -= 1088; src = Wv; N = 64; dst = Wqkv_t + (size_t)1088 * EMB;
                          n0 = (tb & 1) * 32; k0 = (tb >> 1) * 32; }
    else                { tb -= 1152; src = Wo; N = 1024; dst = Wo_t;
                          n0 = (tb & 31) * 32; k0 = (tb >> 5) * 32; }
    __shared__ float tile[32][33];
    const int tx = t & 31, ty = t >> 5;
#pragma unroll
    for (int i = 0; i < 32; i += 8)
        tile[ty + i][tx] = src[(size_t)(k0 + ty + i) * N + n0 + tx];
    __syncthreads();
#pragma unroll
    for (int i = 0; i < 32; i += 8)
        dst[(size_t)(n0 + ty + i) * EMB + k0 + tx] = f2bf(tile[tx][ty + i]);
}

// bf16 MFMA GEMM (r3-proven): C(M,N) = A(M,K) @ Bt(N,K)^T [+ bias].
// 128x128 tile, BK=32, 256 thr = 2x2 waves, each wave 64x64 (4x4 mfma).
// WRITE_VT: cols >= 1088 additionally write transposed bf16 to Vt[b][d][n].
template<bool HAS_BIAS, bool WRITE_VT, typename OutT>
__global__ __launch_bounds__(256) void gemm_bf16(const ushort_t* __restrict__ A,
                                                 const ushort_t* __restrict__ Bt,
                                                 const float* __restrict__ bias,
                                                 OutT* __restrict__ C,
                                                 ushort_t* __restrict__ Vt,
                                                 int M, int N, int K) {
    __shared__ __align__(16) ushort_t Al[128 * 32];
    __shared__ __align__(16) ushort_t Bl[128 * 32];
    const int t = threadIdx.x;
    const int w = t >> 6, lane = t & 63, quad = lane >> 4, ln = lane & 15;
    const int wm = w >> 1, wn = w & 1;
    const int row0 = blockIdx.y * 128, col0 = blockIdx.x * 128;

    const int r0 = t >> 2, r1 = (t + 256) >> 2;
    const int lc0 = (t & 3) ^ ((r0 >> 1) & 3);
    const int lc1 = (t & 3) ^ ((r1 >> 1) & 3);
    const ushort_t* ga0 = A + (size_t)(row0 + r0) * K + lc0 * 8;
    const ushort_t* ga1 = A + (size_t)(row0 + r1) * K + lc1 * 8;
    const ushort_t* gb0 = Bt + (size_t)(col0 + r0) * K + lc0 * 8;
    const ushort_t* gb1 = Bt + (size_t)(col0 + r1) * K + lc1 * 8;
    ushort_t* lA0 = Al + w * 512;
    ushort_t* lA1 = Al + 2048 + w * 512;
    ushort_t* lB0 = Bl + w * 512;
    ushort_t* lB1 = Bl + 2048 + w * 512;

    f32x4 acc[4][4] = {};
    const int sw = (ln >> 1) & 3;
    for (int k0 = 0; k0 < K; k0 += 32) {
        GL16(ga0, lA0); GL16(ga1, lA1);
        GL16(gb0, lB0); GL16(gb1, lB1);
        ga0 += 32; ga1 += 32; gb0 += 32; gb1 += 32;
        __syncthreads();

        s16x8 af[4], bf[4];
#pragma unroll
        for (int mt = 0; mt < 4; ++mt) {
            const int r = wm * 64 + mt * 16 + ln;
            af[mt] = *(const s16x8*)&Al[r * 32 + ((quad ^ sw) * 8)];
        }
#pragma unroll
        for (int nt = 0; nt < 4; ++nt) {
            const int r = wn * 64 + nt * 16 + ln;
            bf[nt] = *(const s16x8*)&Bl[r * 32 + ((quad ^ sw) * 8)];
        }
#pragma unroll
        for (int mt = 0; mt < 4; ++mt)
#pragma unroll
            for (int nt = 0; nt < 4; ++nt)
                acc[mt][nt] = __builtin_amdgcn_mfma_f32_16x16x32_bf16(
                    af[mt], bf[nt], acc[mt][nt], 0, 0, 0);
        __syncthreads();
    }

#pragma unroll
    for (int nt = 0; nt < 4; ++nt) {
        const int col = col0 + wn * 64 + nt * 16 + ln;
        const float bv = HAS_BIAS ? bias[col] : 0.f;
#pragma unroll
        for (int mt = 0; mt < 4; ++mt) {
#pragma unroll
            for (int r = 0; r < 4; ++r) {
                const int row = row0 + wm * 64 + mt * 16 + quad * 4 + r;
                store_out(&C[(size_t)row * N + col], acc[mt][nt][r] + bv);
            }
            if (WRITE_VT && col >= 1088) {
                const int d = col - 1088;
                const int n = row0 + wm * 64 + mt * 16 + quad * 4;  // 4 consec rows
                const int bb = n >> 11, nn = n & 2047;
                ushort_t tmp[4] = {f2bf(acc[mt][nt][0]), f2bf(acc[mt][nt][1]),
                                   f2bf(acc[mt][nt][2]), f2bf(acc[mt][nt][3])};
                *(uint2*)&Vt[((size_t)bb * 64 + d) * NQ + nn] = *(uint2*)tmp;
            }
        }
    }
}

// ---- attention LDS helpers: [row][chunk], chunk=16B of inner dim;
// physical chunk = logical ^ (row&7). Staging by 512 threads. ----
// 64-row tile (K/V): one GL16 per thread. u = t: row=u>>3, chunk=u&7.
__device__ __forceinline__ void stage64(ushort_t* lds, const ushort_t* g,
                                        size_t rstride, int t) {
    const int row = t >> 3, pc = t & 7;
    const int lc = pc ^ (row & 7);
    GL16(g + (size_t)row * rstride + lc * 8, lds + (size_t)(t >> 3 << 3) * 8
                                                + 0 * 0 + (size_t)0 + ((size_t)(t & ~63)) * 8);
}

// NOTE: the lds pointer passed to GL16 must be wave-uniform-base + lane*16B.
// For u = t, elem offset = u*8 = (t&~63)*8 + lane*8 (8 elems = 16B). The
// expression above computes exactly (t&~63)*8.   (row math only affects global)

__device__ __forceinline__ void stage128(ushort_t* lds, const ushort_t* g,
                                         size_t rstride, int t) {
#pragma unroll
    for (int it = 0; it < 2; ++it) {
        const int u = it * 512 + t;
        const int row = u >> 3, pc = u & 7;
        const int lc = pc ^ (row & 7);
        GL16(g + (size_t)row * rstride + lc * 8, lds + (size_t)(u & ~63) * 8);
    }
}

__device__ __forceinline__ s16x8 frag(const ushort_t* lds, int row, int lc) {
    const int phys = lc ^ (row & 7);
    return *(const s16x8*)&lds[row * 64 + phys * 8];
}

// Flash attention, r9 math verbatim, 128-row q-tiles, 8 waves (512 thr).
// Grid 512: qt = 15 - (bid>>5) (heavy-first LPT); rem = bid&31 -> b, h.
// Wave w owns q-rows w*16..w*16+15 of the 128-row tile. K-tiles of 64 keys,
// double-buffered via global_load_lds; iters = 2*qt+2.
__global__ __launch_bounds__(512, 6) void attn_mfma(const ushort_t* __restrict__ QKV,
                                                    const ushort_t* __restrict__ Vt,
                                                    ushort_t* __restrict__ Z) {
    const int bid = blockIdx.x;
    const int qt = 15 - (bid >> 5);
    const int rem = bid & 31, b = rem >> 4, h = rem & 15;
    const int t = threadIdx.x;
    const int w = t >> 6, lane = t & 63, quad = lane >> 4, ln = lane & 15;

    __shared__ __align__(16) ushort_t QPs[128 * 64];       // 16 KB: Q stage, then P
    __shared__ __align__(16) ushort_t Kl[2][64 * 64];      // 16 KB
    __shared__ __align__(16) ushort_t Vl[2][64 * 64];      // 16 KB -> 48 KB total

    const ushort_t* Kg = QKV + (size_t)b * NQ * NKV + 1024;   // [key][d], row=NKV
    const ushort_t* Vg = Vt + (size_t)b * 64 * NQ;            // [d][key], row=NQ

    stage128(QPs, QKV + (size_t)(b * NQ + qt * 128) * NKV + h * HD, NKV, t);
    {   // stage K/V tile 0 (u = t covers 64 rows x 8 chunks)
        const int row = t >> 3, pc = t & 7;
        const int lc = pc ^ (row & 7);
        GL16(Kg + (size_t)row * NKV + lc * 8, Kl[0] + (size_t)(t & ~63) * 8);
        GL16(Vg + (size_t)row * NQ + lc * 8, Vl[0] + (size_t)(t & ~63) * 8);
    }
    __syncthreads();   // drains vmcnt -> Q, K0, V0 ready

    const s16x8 aQ0 = frag(QPs, w * 16 + ln, quad);
    const s16x8 aQ1 = frag(QPs, w * 16 + ln, 4 + quad);
    ushort_t* Pw = QPs;   // reused as P; wave w touches only rows w*16..+15

    f32x4 o[4];
#pragma unroll
    for (int ii = 0; ii < 4; ++ii) o[ii] = f32x4{0.f, 0.f, 0.f, 0.f};
    float mrow[4], lrow[4];
#pragma unroll
    for (int r = 0; r < 4; ++r) { mrow[r] = -1e30f; lrow[r] = 0.f; }

    const int niter = 2 * qt + 2;
#pragma unroll 1
    for (int jt = 0; jt < niter; ++jt) {
        const int cur = jt & 1;
        if (jt + 1 < niter) {   // prefetch next K/V tile; drained by end barrier
            const int row = t >> 3, pc = t & 7;
            const int lc = pc ^ (row & 7);
            GL16(Kg + (size_t)((jt + 1) * 64 + row) * NKV + lc * 8,
                 Kl[cur ^ 1] + (size_t)(t & ~63) * 8);
            GL16(Vg + (size_t)row * NQ + (jt + 1) * 64 + lc * 8,
                 Vl[cur ^ 1] + (size_t)(t & ~63) * 8);
        }
        const ushort_t* Kc = Kl[cur];
        const ushort_t* Vc = Vl[cur];

        // S = Q K^T
        f32x4 s[4];
#pragma unroll
        for (int nt = 0; nt < 4; ++nt) {
            f32x4 acc = f32x4{0.f, 0.f, 0.f, 0.f};
            const s16x8 b0 = frag(Kc, nt * 16 + ln, quad);
            const s16x8 b1 = frag(Kc, nt * 16 + ln, 4 + quad);
            acc = __builtin_amdgcn_mfma_f32_16x16x32_bf16(aQ0, b0, acc, 0, 0, 0);
            acc = __builtin_amdgcn_mfma_f32_16x16x32_bf16(aQ1, b1, acc, 0, 0, 0);
            s[nt] = acc;
        }

        // scale + causal mask + online softmax (global q = qt*128 + w*16 + quad*4 + r)
        const bool diag = (jt >= 2 * qt);   // last two tiles straddle the diagonal
        float rmax[4];
#pragma unroll
        for (int r = 0; r < 4; ++r) rmax[r] = -1e30f;
#pragma unroll
        for (int nt = 0; nt < 4; ++nt)
#pragma unroll
            for (int r = 0; r < 4; ++r) {
                float v = s[nt][r] * 0.125f;
                if (diag && (jt * 64 + nt * 16 + ln) >
                            (qt * 128 + w * 16 + quad * 4 + r)) v = -1e30f;
                s[nt][r] = v;
                rmax[r] = fmaxf(rmax[r], v);
            }
#pragma unroll
        for (int r = 0; r < 4; ++r) {
            rmax[r] = fmaxf(rmax[r], __shfl_xor(rmax[r], 1));
            rmax[r] = fmaxf(rmax[r], __shfl_xor(rmax[r], 2));
            rmax[r] = fmaxf(rmax[r], __shfl_xor(rmax[r], 4));
            rmax[r] = fmaxf(rmax[r], __shfl_xor(rmax[r], 8));
        }
        float alpha[4], rsum[4];
#pragma unroll
        for (int r = 0; r < 4; ++r) {
            const float mnew = fmaxf(mrow[r], rmax[r]);
            alpha[r] = __expf(mrow[r] - mnew);
            mrow[r] = mnew;
            rsum[r] = 0.f;
        }
#pragma unroll
        for (int nt = 0; nt < 4; ++nt)
#pragma unroll
            for (int r = 0; r < 4; ++r) {
                const float pv = __expf(s[nt][r] - mrow[r]);
                s[nt][r] = pv;
                rsum[r] += pv;
            }
#pragma unroll
        for (int r = 0; r < 4; ++r) {
            rsum[r] += __shfl_xor(rsum[r], 1);
            rsum[r] += __shfl_xor(rsum[r], 2);
            rsum[r] += __shfl_xor(rsum[r], 4);
            rsum[r] += __shfl_xor(rsum[r], 8);
            lrow[r] = lrow[r] * alpha[r] + rsum[r];
        }
#pragma unroll
        for (int ntd = 0; ntd < 4; ++ntd)
#pragma unroll
            for (int r = 0; r < 4; ++r) o[ntd][r] *= alpha[r];

        // P -> per-wave rows of QPs (XOR-swizzled, r9 layout), re-read in A-layout.
#pragma unroll
        for (int nt = 0; nt < 4; ++nt)
#pragma unroll
            for (int r = 0; r < 4; ++r) {
                const int prow = quad * 4 + r;
                const int pc = (nt * 2 + (ln >> 3)) ^ (prow & 7);
                Pw[(w * 16 + prow) * 64 + pc * 8 + (ln & 7)] = f2bf(s[nt][r]);
            }
        asm volatile("s_waitcnt lgkmcnt(0)" ::: "memory");

        const s16x8 aP0 = frag(Pw, w * 16 + ln, quad);
        const s16x8 aP1 = frag(Pw, w * 16 + ln, 4 + quad);
#pragma unroll
        for (int ntd = 0; ntd < 4; ++ntd) {
            const s16x8 b0 = frag(Vc, ntd * 16 + ln, quad);
            const s16x8 b1 = frag(Vc, ntd * 16 + ln, 4 + quad);
            o[ntd] = __builtin_amdgcn_mfma_f32_16x16x32_bf16(aP0, b0, o[ntd], 0, 0, 0);
            o[ntd] = __builtin_amdgcn_mfma_f32_16x16x32_bf16(aP1, b1, o[ntd], 0, 0, 0);
        }
        __syncthreads();   // buffer handoff + drains prefetch for next iter
    }

    // epilogue: normalize + store Z (bf16)
    float invl[4];
#pragma unroll
    for (int r = 0; r < 4; ++r) invl[r] = 1.f / lrow[r];
#pragma unroll
    for (int ntd = 0; ntd < 4; ++ntd)
#pragma unroll
        for (int r = 0; r < 4; ++r) {
            const size_t row = (size_t)(b * NQ + qt * 128 + w * 16 + quad * 4 + r);
            Z[row * EMB + h * HD + ntd * 16 + ln] = f2bf(o[ntd][r] * invl[r]);
        }
}

extern "C" void kernel_launch(void* const* d_in, const int* in_sizes, int n_in,
                              void* d_out, int out_size, void* d_ws, size_t ws_size,
                              hipStream_t stream) {
    const float* x  = (const float*)d_in[0];
    const float* Wq = (const float*)d_in[1];
    const float* Wk = (const float*)d_in[2];
    const float* Wv = (const float*)d_in[3];
    const float* Wo = (const float*)d_in[4];
    const float* bo = (const float*)d_in[5];
    float* out = (float*)d_out;

    const int M = BATCH * NQ;                                   // 4096
    char* ws = (char*)d_ws;
    ushort_t* xb     = (ushort_t*)ws;                                      // 8 MB
    ushort_t* Wqkv_t = (ushort_t*)(ws + (size_t)8  * 1024 * 1024);         // 2.25 MB
    ushort_t* Wo_t   = (ushort_t*)(ws + (size_t)11 * 1024 * 1024);         // 2 MB
    ushort_t* QKV    = (ushort_t*)(ws + (size_t)13 * 1024 * 1024);         // 9.22 MB
    ushort_t* Vt     = (ushort_t*)(ws + (size_t)23 * 1024 * 1024);         // 0.5 MB
    ushort_t* Zb     = (ushort_t*)(ws + (size_t)24 * 1024 * 1024);         // 8 MB

    prep<<<dim3(6272), dim3(256), 0, stream>>>(x, Wq, Wk, Wv, Wo, xb, Wqkv_t, Wo_t);
    gemm_bf16<false, true, ushort_t><<<dim3(NKV / 128, M / 128), dim3(256), 0, stream>>>(
        xb, Wqkv_t, nullptr, QKV, Vt, M, NKV, EMB);
    attn_mfma<<<dim3(512), dim3(512), 0, stream>>>(QKV, Vt, Zb);
    gemm_bf16<true, false, float><<<dim3(EMB / 128, M / 128), dim3(256), 0, stream>>>(
        Zb, Wo_t, bo, out, nullptr, M, EMB, EMB);
}

// Round 12
// 194.630 us; speedup vs baseline: 1.3018x; 1.3018x over previous
//
#include <hip/hip_runtime.h>
#include <hip/hip_bf16.h>

// B=2, N=2048, E=1024, H=16, D=64 (MQA). out = softmax(causal(QK^T/8)) V @ Wo + bo
//
// Round 12: r11's 128-row attention tile with the spill bug fixed.
//   - attn: 512 thr / 8 waves, __launch_bounds__(512,4) (r11's (512,6) forced
//     VGPR<=64 -> 40 VGPR + 20MB scratch spills; (512,4) allows ~128).
//     Grid 512: bids c and c+256 have qt summing to 15 -> every CU pair = 34 iters.
//   - GEMMs: r9's measured-better 64x128 tiles, Vt-write fused in QKV epilogue.
//   - prep, softmax math, P layout, staging swizzle: r9 verbatim (proven).

#define NQ 2048
#define BATCH 2
#define HEADS 16
#define HD 64
#define EMB 1024
#define NKV 1152   // 1024 Q cols + 64 K + 64 V

typedef short s16x8 __attribute__((ext_vector_type(8)));
typedef float f32x4 __attribute__((ext_vector_type(4)));
typedef unsigned short ushort_t;

__device__ __forceinline__ ushort_t f2bf(float f) {
    unsigned u = __builtin_bit_cast(unsigned, f);
    u += 0x7fff + ((u >> 16) & 1);          // RNE
    return (ushort_t)(u >> 16);
}

__device__ __forceinline__ void store_out(float* p, float v) { *p = v; }
__device__ __forceinline__ void store_out(ushort_t* p, float v) { *p = f2bf(v); }

// async global->LDS, 16B per lane. LDS dest = wave-uniform base + lane*16.
#define GL16(g, l)                                                                  \
    __builtin_amdgcn_global_load_lds(                                               \
        (const __attribute__((address_space(1))) unsigned int*)(g),                 \
        (__attribute__((address_space(3))) unsigned int*)(l), 16, 0, 0)

// Fused prep: blocks [0,4096): x fp32->bf16. Blocks [4096,6272): 32x32 transpose
// tiles of Wq/Wk/Wv (packed into Wqkv_t, N-major) and Wo -> Wo_t.
__global__ __launch_bounds__(256) void prep(const float* __restrict__ x,
                                            const float* __restrict__ Wq,
                                            const float* __restrict__ Wk,
                                            const float* __restrict__ Wv,
                                            const float* __restrict__ Wo,
                                            ushort_t* __restrict__ xb,
                                            ushort_t* __restrict__ Wqkv_t,
                                            ushort_t* __restrict__ Wo_t) {
    const int bid = blockIdx.x, t = threadIdx.x;
    if (bid < 4096) {
        const int i = bid * 1024 + t * 4;
        const float4 v = *(const float4*)&x[i];
        ushort_t o[4] = {f2bf(v.x), f2bf(v.y), f2bf(v.z), f2bf(v.w)};
        *(uint2*)&xb[i] = *(uint2*)o;
        return;
    }
    int tb = bid - 4096;
    const float* src; ushort_t* dst; int N, n0, k0;
    if (tb < 1024)      { src = Wq; N = 1024; dst = Wqkv_t;
                          n0 = (tb & 31) * 32; k0 = (tb >> 5) * 32; }
    else if (tb < 1088) { tb -= 1024; src = Wk; N = 64; dst = Wqkv_t + (size_t)1024 * EMB;
                          n0 = (tb & 1) * 32; k0 = (tb >> 1) * 32; }
    else if (tb < 1152) { tb -= 1088; src = Wv; N = 64; dst = Wqkv_t + (size_t)1088 * EMB;
                          n0 = (tb & 1) * 32; k0 = (tb >> 1) * 32; }
    else                { tb -= 1152; src = Wo; N = 1024; dst = Wo_t;
                          n0 = (tb & 31) * 32; k0 = (tb >> 5) * 32; }
    __shared__ float tile[32][33];
    const int tx = t & 31, ty = t >> 5;
#pragma unroll
    for (int i = 0; i < 32; i += 8)
        tile[ty + i][tx] = src[(size_t)(k0 + ty + i) * N + n0 + tx];
    __syncthreads();
#pragma unroll
    for (int i = 0; i < 32; i += 8)
        dst[(size_t)(n0 + ty + i) * EMB + k0 + tx] = f2bf(tile[tx][ty + i]);
}

// bf16 MFMA GEMM: C(M,N) = A(M,K) @ Bt(N,K)^T [+ bias]. 64x128 tile, BK=32.
// WRITE_VT: cols >= 1088 additionally write transposed bf16 to Vt[b][d][n].
template<bool HAS_BIAS, bool WRITE_VT, typename OutT>
__global__ __launch_bounds__(256) void gemm_bf16(const ushort_t* __restrict__ A,
                                                 const ushort_t* __restrict__ Bt,
                                                 const float* __restrict__ bias,
                                                 OutT* __restrict__ C,
                                                 ushort_t* __restrict__ Vt,
                                                 int M, int N, int K) {
    __shared__ __align__(16) ushort_t Al[64 * 32];
    __shared__ __align__(16) ushort_t Bl[128 * 32];
    const int t = threadIdx.x;
    const int w = t >> 6, lane = t & 63, quad = lane >> 4, ln = lane & 15;
    const int row0 = blockIdx.y * 64, col0 = blockIdx.x * 128;

    const int rA = t >> 2;
    const int lcA = (t & 3) ^ ((rA >> 1) & 3);
    const int rB1 = 64 + rA;
    const ushort_t* ga  = A  + (size_t)(row0 + rA) * K + lcA * 8;
    const ushort_t* gb0 = Bt + (size_t)(col0 + rA) * K + lcA * 8;
    const ushort_t* gb1 = Bt + (size_t)(col0 + rB1) * K + lcA * 8;
    ushort_t* lA  = Al + w * 512;
    ushort_t* lB0 = Bl + w * 512;
    ushort_t* lB1 = Bl + 2048 + w * 512;

    f32x4 acc[4][2] = {};
    const int sw = (ln >> 1) & 3;
    for (int k0 = 0; k0 < K; k0 += 32) {
        GL16(ga, lA); GL16(gb0, lB0); GL16(gb1, lB1);
        ga += 32; gb0 += 32; gb1 += 32;
        __syncthreads();

        s16x8 af[4], bf[2];
#pragma unroll
        for (int mt = 0; mt < 4; ++mt)
            af[mt] = *(const s16x8*)&Al[(mt * 16 + ln) * 32 + ((quad ^ sw) * 8)];
#pragma unroll
        for (int nt = 0; nt < 2; ++nt)
            bf[nt] = *(const s16x8*)&Bl[(w * 32 + nt * 16 + ln) * 32 + ((quad ^ sw) * 8)];
#pragma unroll
        for (int mt = 0; mt < 4; ++mt)
#pragma unroll
            for (int nt = 0; nt < 2; ++nt)
                acc[mt][nt] = __builtin_amdgcn_mfma_f32_16x16x32_bf16(
                    af[mt], bf[nt], acc[mt][nt], 0, 0, 0);
        __syncthreads();
    }

#pragma unroll
    for (int nt = 0; nt < 2; ++nt) {
        const int col = col0 + w * 32 + nt * 16 + ln;
        const float bv = HAS_BIAS ? bias[col] : 0.f;
#pragma unroll
        for (int mt = 0; mt < 4; ++mt) {
#pragma unroll
            for (int r = 0; r < 4; ++r) {
                const int row = row0 + mt * 16 + quad * 4 + r;
                store_out(&C[(size_t)row * N + col], acc[mt][nt][r] + bv);
            }
            if (WRITE_VT && col >= 1088) {
                const int d = col - 1088;
                const int n = row0 + mt * 16 + quad * 4;   // 4 consecutive rows
                const int bb = n >> 11, nn = n & 2047;
                ushort_t tmp[4] = {f2bf(acc[mt][nt][0]), f2bf(acc[mt][nt][1]),
                                   f2bf(acc[mt][nt][2]), f2bf(acc[mt][nt][3])};
                *(uint2*)&Vt[((size_t)bb * 64 + d) * NQ + nn] = *(uint2*)tmp;
            }
        }
    }
}

// ---- attention LDS helpers: [row][chunk], chunk=16B of inner dim;
// physical chunk = logical ^ (row&7). ----
__device__ __forceinline__ s16x8 frag(const ushort_t* lds, int row, int lc) {
    const int phys = lc ^ (row & 7);
    return *(const s16x8*)&lds[row * 64 + phys * 8];
}

// Flash attention, r9 math verbatim, 128-row q-tiles, 8 waves (512 thr).
// Grid 512: grp = bid>>8, c = bid&255; qt = grp ? (c>>5) : 15-(c>>5)
// (bids c and c+256 sum to qt=15 -> 34 tile-iters per CU pair, heavy-first).
// Wave w (0..7) owns q-rows w*16..+15. K/V tiles of 64 keys double-buffered
// via global_load_lds (r10 lesson: cross-wave LDS sharing beats direct-global).
__global__ __launch_bounds__(512, 4) void attn_mfma(const ushort_t* __restrict__ QKV,
                                                    const ushort_t* __restrict__ Vt,
                                                    ushort_t* __restrict__ Z) {
    const int bid = blockIdx.x;
    const int grp = bid >> 8, c = bid & 255;
    const int qt = grp ? (c >> 5) : 15 - (c >> 5);
    const int b = (c >> 4) & 1, h = c & 15;
    const int t = threadIdx.x;
    const int w = t >> 6, lane = t & 63, quad = lane >> 4, ln = lane & 15;

    __shared__ __align__(16) ushort_t QPs[128 * 64];       // 16 KB: Q stage, then P
    __shared__ __align__(16) ushort_t Kl[2][64 * 64];      // 16 KB
    __shared__ __align__(16) ushort_t Vl[2][64 * 64];      // 16 KB -> 48 KB total

    const ushort_t* Kg = QKV + (size_t)b * NQ * NKV + 1024;   // [key][d], row=NKV
    const ushort_t* Vg = Vt + (size_t)b * 64 * NQ;            // [d][key], row=NQ

    {   // stage Q (128 rows x 8 chunks = 1024 GL16s over 512 thr x 2)
#pragma unroll
        for (int it = 0; it < 2; ++it) {
            const int u = it * 512 + t;
            const int row = u >> 3, pc = u & 7;
            const int lc = pc ^ (row & 7);
            GL16(QKV + (size_t)(b * NQ + qt * 128 + row) * NKV + h * HD + lc * 8,
                 QPs + (size_t)(u & ~63) * 8);
        }
        // stage K/V tile 0 (u = t covers 64 rows x 8 chunks)
        const int row = t >> 3, pc = t & 7;
        const int lc = pc ^ (row & 7);
        GL16(Kg + (size_t)row * NKV + lc * 8, Kl[0] + (size_t)(t & ~63) * 8);
        GL16(Vg + (size_t)row * NQ + lc * 8, Vl[0] + (size_t)(t & ~63) * 8);
    }
    __syncthreads();   // drains vmcnt -> Q, K0, V0 ready

    const s16x8 aQ0 = frag(QPs, w * 16 + ln, quad);
    const s16x8 aQ1 = frag(QPs, w * 16 + ln, 4 + quad);
    ushort_t* Pw = QPs;   // reused as P; wave w touches only rows w*16..+15

    f32x4 o[4];
#pragma unroll
    for (int ii = 0; ii < 4; ++ii) o[ii] = f32x4{0.f, 0.f, 0.f, 0.f};
    float mrow[4], lrow[4];
#pragma unroll
    for (int r = 0; r < 4; ++r) { mrow[r] = -1e30f; lrow[r] = 0.f; }

    const int niter = 2 * qt + 2;
#pragma unroll 1
    for (int jt = 0; jt < niter; ++jt) {
        const int cur = jt & 1;
        if (jt + 1 < niter) {   // prefetch next K/V tile; drained by end barrier
            const int row = t >> 3, pc = t & 7;
            const int lc = pc ^ (row & 7);
            GL16(Kg + (size_t)((jt + 1) * 64 + row) * NKV + lc * 8,
                 Kl[cur ^ 1] + (size_t)(t & ~63) * 8);
            GL16(Vg + (size_t)row * NQ + (jt + 1) * 64 + lc * 8,
                 Vl[cur ^ 1] + (size_t)(t & ~63) * 8);
        }
        const ushort_t* Kc = Kl[cur];
        const ushort_t* Vc = Vl[cur];

        // S = Q K^T
        f32x4 s[4];
#pragma unroll
        for (int nt = 0; nt < 4; ++nt) {
            f32x4 acc = f32x4{0.f, 0.f, 0.f, 0.f};
            const s16x8 b0 = frag(Kc, nt * 16 + ln, quad);
            const s16x8 b1 = frag(Kc, nt * 16 + ln, 4 + quad);
            acc = __builtin_amdgcn_mfma_f32_16x16x32_bf16(aQ0, b0, acc, 0, 0, 0);
            acc = __builtin_amdgcn_mfma_f32_16x16x32_bf16(aQ1, b1, acc, 0, 0, 0);
            s[nt] = acc;
        }

        // scale + causal mask + online softmax (global q = qt*128 + w*16 + quad*4 + r)
        const bool diag = (jt >= 2 * qt);   // last two tiles straddle the diagonal
        float rmax[4];
#pragma unroll
        for (int r = 0; r < 4; ++r) rmax[r] = -1e30f;
#pragma unroll
        for (int nt = 0; nt < 4; ++nt)
#pragma unroll
            for (int r = 0; r < 4; ++r) {
                float v = s[nt][r] * 0.125f;
                if (diag && (jt * 64 + nt * 16 + ln) >
                            (qt * 128 + w * 16 + quad * 4 + r)) v = -1e30f;
                s[nt][r] = v;
                rmax[r] = fmaxf(rmax[r], v);
            }
#pragma unroll
        for (int r = 0; r < 4; ++r) {
            rmax[r] = fmaxf(rmax[r], __shfl_xor(rmax[r], 1));
            rmax[r] = fmaxf(rmax[r], __shfl_xor(rmax[r], 2));
            rmax[r] = fmaxf(rmax[r], __shfl_xor(rmax[r], 4));
            rmax[r] = fmaxf(rmax[r], __shfl_xor(rmax[r], 8));
        }
        float alpha[4], rsum[4];
#pragma unroll
        for (int r = 0; r < 4; ++r) {
            const float mnew = fmaxf(mrow[r], rmax[r]);
            alpha[r] = __expf(mrow[r] - mnew);
            mrow[r] = mnew;
            rsum[r] = 0.f;
        }
#pragma unroll
        for (int nt = 0; nt < 4; ++nt)
#pragma unroll
            for (int r = 0; r < 4; ++r) {
                const float pv = __expf(s[nt][r] - mrow[r]);
                s[nt][r] = pv;
                rsum[r] += pv;
            }
#pragma unroll
        for (int r = 0; r < 4; ++r) {
            rsum[r] += __shfl_xor(rsum[r], 1);
            rsum[r] += __shfl_xor(rsum[r], 2);
            rsum[r] += __shfl_xor(rsum[r], 4);
            rsum[r] += __shfl_xor(rsum[r], 8);
            lrow[r] = lrow[r] * alpha[r] + rsum[r];
        }
#pragma unroll
        for (int ntd = 0; ntd < 4; ++ntd)
#pragma unroll
            for (int r = 0; r < 4; ++r) o[ntd][r] *= alpha[r];

        // P -> per-wave rows of QPs (XOR-swizzled, r9 layout), re-read in A-layout.
#pragma unroll
        for (int nt = 0; nt < 4; ++nt)
#pragma unroll
            for (int r = 0; r < 4; ++r) {
                const int prow = quad * 4 + r;
                const int pc = (nt * 2 + (ln >> 3)) ^ (prow & 7);
                Pw[(w * 16 + prow) * 64 + pc * 8 + (ln & 7)] = f2bf(s[nt][r]);
            }
        asm volatile("s_waitcnt lgkmcnt(0)" ::: "memory");

        const s16x8 aP0 = frag(Pw, w * 16 + ln, quad);
        const s16x8 aP1 = frag(Pw, w * 16 + ln, 4 + quad);
#pragma unroll
        for (int ntd = 0; ntd < 4; ++ntd) {
            const s16x8 b0 = frag(Vc, ntd * 16 + ln, quad);
            const s16x8 b1 = frag(Vc, ntd * 16 + ln, 4 + quad);
            o[ntd] = __builtin_amdgcn_mfma_f32_16x16x32_bf16(aP0, b0, o[ntd], 0, 0, 0);
            o[ntd] = __builtin_amdgcn_mfma_f32_16x16x32_bf16(aP1, b1, o[ntd], 0, 0, 0);
        }
        __syncthreads();   // buffer handoff + drains prefetch for next iter
    }

    // epilogue: normalize + store Z (bf16)
    float invl[4];
#pragma unroll
    for (int r = 0; r < 4; ++r) invl[r] = 1.f / lrow[r];
#pragma unroll
    for (int ntd = 0; ntd < 4; ++ntd)
#pragma unroll
        for (int r = 0; r < 4; ++r) {
            const size_t row = (size_t)(b * NQ + qt * 128 + w * 16 + quad * 4 + r);
            Z[row * EMB + h * HD + ntd * 16 + ln] = f2bf(o[ntd][r] * invl[r]);
        }
}

extern "C" void kernel_launch(void* const* d_in, const int* in_sizes, int n_in,
                              void* d_out, int out_size, void* d_ws, size_t ws_size,
                              hipStream_t stream) {
    const float* x  = (const float*)d_in[0];
    const float* Wq = (const float*)d_in[1];
    const float* Wk = (const float*)d_in[2];
    const float* Wv = (const float*)d_in[3];
    const float* Wo = (const float*)d_in[4];
    const float* bo = (const float*)d_in[5];
    float* out = (float*)d_out;

    const int M = BATCH * NQ;                                   // 4096
    char* ws = (char*)d_ws;
    ushort_t* xb     = (ushort_t*)ws;                                      // 8 MB
    ushort_t* Wqkv_t = (ushort_t*)(ws + (size_t)8  * 1024 * 1024);         // 2.25 MB
    ushort_t* Wo_t   = (ushort_t*)(ws + (size_t)11 * 1024 * 1024);         // 2 MB
    ushort_t* QKV    = (ushort_t*)(ws + (size_t)13 * 1024 * 1024);         // 9.22 MB
    ushort_t* Vt     = (ushort_t*)(ws + (size_t)23 * 1024 * 1024);         // 0.5 MB
    ushort_t* Zb     = (ushort_t*)(ws + (size_t)24 * 1024 * 1024);         // 8 MB

    prep<<<dim3(6272), dim3(256), 0, stream>>>(x, Wq, Wk, Wv, Wo, xb, Wqkv_t, Wo_t);
    gemm_bf16<false, true, ushort_t><<<dim3(NKV / 128, M / 64), dim3(256), 0, stream>>>(
        xb, Wqkv_t, nullptr, QKV, Vt, M, NKV, EMB);
    attn_mfma<<<dim3(512), dim3(512), 0, stream>>>(QKV, Vt, Zb);
    gemm_bf16<true, false, float><<<dim3(EMB / 128, M / 64), dim3(256), 0, stream>>>(
        Zb, Wo_t, bo, out, nullptr, M, EMB, EMB);
}